// Round 1
// baseline (146.049 us; speedup 1.0000x reference)
//
#include <hip/hip_runtime.h>
#include <stddef.h>

// DeepProbLog addition reasoner:
//   out[b,k] = sum_{i+j==k} p1[b,i]*p2[b,j], normalized by (row-sum + 1e-9)
// B = 1048576, 10 probs per input row, 19 output bins per row.
// Memory-bound: ~164 MB total traffic -> ~26 us floor at 6.3 TB/s.

#define EPS 1e-9f

constexpr int THREADS = 256;   // threads per block == rows per block
constexpr int ROWS    = 256;

__global__ __launch_bounds__(THREADS)
void dpl_add_kernel(const float* __restrict__ p1,
                    const float* __restrict__ p2,
                    float* __restrict__ out,
                    int B) {
    // LDS staging for fully coalesced global traffic.
    __shared__ __align__(16) float sa[ROWS * 10];   // 10240 B
    __shared__ __align__(16) float sb[ROWS * 10];   // 10240 B
    __shared__ __align__(16) float so[ROWS * 19];   // 19456 B

    const int tid  = threadIdx.x;
    const int row0 = blockIdx.x * ROWS;
    const bool full = (row0 + ROWS) <= B;

    // ---- stage inputs: coalesced float4 loads ----
    if (full) {
        const float4* g1 = reinterpret_cast<const float4*>(p1 + (size_t)row0 * 10);
        const float4* g2 = reinterpret_cast<const float4*>(p2 + (size_t)row0 * 10);
        float4* s1 = reinterpret_cast<float4*>(sa);
        float4* s2 = reinterpret_cast<float4*>(sb);
        for (int i = tid; i < ROWS * 10 / 4; i += THREADS) {  // 640 float4 per input
            s1[i] = g1[i];
            s2[i] = g2[i];
        }
    } else {
        int n = B - row0; if (n < 0) n = 0;
        for (int i = tid; i < n * 10; i += THREADS) {
            sa[i] = p1[(size_t)row0 * 10 + i];
            sb[i] = p2[(size_t)row0 * 10 + i];
        }
    }
    __syncthreads();

    // ---- per-thread compute: one row each ----
    const int b = row0 + tid;
    float s[19];
    #pragma unroll
    for (int k = 0; k < 19; ++k) s[k] = 0.0f;

    if (b < B) {
        float a[10], c[10];
        #pragma unroll
        for (int i = 0; i < 10; ++i) {
            a[i] = sa[tid * 10 + i];
            c[i] = sb[tid * 10 + i];
        }
        // binned outer product: s[i+j] += a[i]*c[j], (i,j) lexicographic
        // (matches reference T@M accumulation order over flattened ij)
        #pragma unroll
        for (int i = 0; i < 10; ++i) {
            #pragma unroll
            for (int j = 0; j < 10; ++j) {
                s[i + j] = fmaf(a[i], c[j], s[i + j]);
            }
        }
        float tot = 0.0f;
        #pragma unroll
        for (int k = 0; k < 19; ++k) tot += s[k];
        const float den = tot + EPS;
        #pragma unroll
        for (int k = 0; k < 19; ++k) s[k] = s[k] / den;  // exact divide, matches ref
    }

    // ---- stage output rows in LDS ----
    // stride 19 (odd) -> lanes hit all 32 banks, only free 2-way aliasing
    #pragma unroll
    for (int k = 0; k < 19; ++k) so[tid * 19 + k] = s[k];
    __syncthreads();

    // ---- coalesced float4 stores ----
    if (full) {
        float4* o4 = reinterpret_cast<float4*>(out + (size_t)row0 * 19);
        const float4* s4 = reinterpret_cast<const float4*>(so);
        for (int i = tid; i < ROWS * 19 / 4; i += THREADS) {  // 1216 float4
            o4[i] = s4[i];
        }
    } else {
        int n = B - row0; if (n < 0) n = 0;
        for (int i = tid; i < n * 19; i += THREADS) {
            out[(size_t)row0 * 19 + i] = so[i];
        }
    }
}

extern "C" void kernel_launch(void* const* d_in, const int* in_sizes, int n_in,
                              void* d_out, int out_size, void* d_ws, size_t ws_size,
                              hipStream_t stream) {
    const float* p1 = (const float*)d_in[0];
    const float* p2 = (const float*)d_in[1];
    float* out = (float*)d_out;
    const int B = in_sizes[0] / 10;   // p1 is [B,10]

    const int grid = (B + ROWS - 1) / ROWS;   // 4096 for B=1048576
    dpl_add_kernel<<<grid, THREADS, 0, stream>>>(p1, p2, out, B);
}

// Round 2
// 145.339 us; speedup vs baseline: 1.0049x; 1.0049x over previous
//
#include <hip/hip_runtime.h>
#include <stddef.h>

// DeepProbLog addition reasoner, round 2: wave-independent streaming.
//   out[b,k] = sum_{i+j==k} p1[b,i]*p2[b,j], normalized by (row-sum + 1e-9)
// B = 1048576. Memory-bound: ~164 MB logical traffic -> ~26 us floor @6.3 TB/s.
//
// Round-1 lesson: ideal traffic but only 2.4 TB/s -> barrier/occupancy bound.
// This version: per-wave LDS slices, ZERO __syncthreads, LDS reused for
// output (20480 B/block -> 8 blocks/CU -> 32 waves/CU).

#define EPS 1e-9f

constexpr int THREADS       = 256;   // 4 waves/block
constexpr int WAVES         = THREADS / 64;
constexpr int ROWS          = THREADS;          // 256 rows per block
constexpr int ROWS_PER_WAVE = 64;
constexpr int SLICE         = 1280;  // floats per wave slice (5120 B): sa|sb, reused for so

__global__ __launch_bounds__(THREADS, 8)
void dpl_add_kernel(const float* __restrict__ p1,
                    const float* __restrict__ p2,
                    float* __restrict__ out,
                    int B) {
    __shared__ __align__(16) float lds[WAVES * SLICE];   // 20480 B

    const int tid   = threadIdx.x;
    const int lane  = tid & 63;
    const int wid   = tid >> 6;
    const int wrow0 = blockIdx.x * ROWS + wid * ROWS_PER_WAVE;

    float* slice = lds + wid * SLICE;   // this wave's private 5120 B

    if (wrow0 + ROWS_PER_WAVE <= B) {
        // ---- stage this wave's 64 rows of each input (coalesced float2) ----
        // 64 rows * 10 f32 = 640 floats = 320 float2 per input; 5 rounds/lane.
        const float2* g1 = reinterpret_cast<const float2*>(p1 + (size_t)wrow0 * 10);
        const float2* g2 = reinterpret_cast<const float2*>(p2 + (size_t)wrow0 * 10);
        float2* s1 = reinterpret_cast<float2*>(slice);         // floats [0,640)
        float2* s2 = reinterpret_cast<float2*>(slice + 640);   // floats [640,1280)
        #pragma unroll
        for (int r = 0; r < 5; ++r) {
            s1[r * 64 + lane] = g1[r * 64 + lane];
            s2[r * 64 + lane] = g2[r * 64 + lane];
        }
        // Wave-synchronous fence: all this wave's LDS writes visible before
        // cross-lane reads. No __syncthreads needed (slice is wave-private).
        asm volatile("s_waitcnt lgkmcnt(0)" ::: "memory");
        __builtin_amdgcn_sched_barrier(0);

        // ---- gather own row into registers (float2, 8B-aligned: 40B rows) ----
        float a[10], c[10];
        #pragma unroll
        for (int i = 0; i < 5; ++i) {
            float2 va = reinterpret_cast<const float2*>(slice)[lane * 5 + i];
            float2 vc = reinterpret_cast<const float2*>(slice + 640)[lane * 5 + i];
            a[2 * i] = va.x; a[2 * i + 1] = va.y;
            c[2 * i] = vc.x; c[2 * i + 1] = vc.y;
        }

        // ---- binned outer product (lexicographic ij, matches reference) ----
        float s[19];
        #pragma unroll
        for (int k = 0; k < 19; ++k) s[k] = 0.0f;
        #pragma unroll
        for (int i = 0; i < 10; ++i) {
            #pragma unroll
            for (int j = 0; j < 10; ++j) {
                s[i + j] = fmaf(a[i], c[j], s[i + j]);
            }
        }
        float tot = 0.0f;
        #pragma unroll
        for (int k = 0; k < 19; ++k) tot += s[k];
        const float den = tot + EPS;
        #pragma unroll
        for (int k = 0; k < 19; ++k) s[k] = s[k] / den;   // exact, matches ref

        // All input reads returned (compute consumed them); fence before we
        // overwrite the slice with output rows.
        asm volatile("s_waitcnt lgkmcnt(0)" ::: "memory");
        __builtin_amdgcn_sched_barrier(0);

        // ---- output rows to LDS (stride 19, odd -> only free 2-way alias) ----
        #pragma unroll
        for (int k = 0; k < 19; ++k) slice[lane * 19 + k] = s[k];

        asm volatile("s_waitcnt lgkmcnt(0)" ::: "memory");
        __builtin_amdgcn_sched_barrier(0);

        // ---- coalesced float4 stores: 64*19 = 1216 floats = 304 float4 ----
        // wrow0 % 64 == 0 -> byte offset wrow0*76 is 16B-aligned.
        float4* o4 = reinterpret_cast<float4*>(out + (size_t)wrow0 * 19);
        const float4* s4 = reinterpret_cast<const float4*>(slice);
        #pragma unroll
        for (int r = 0; r < 5; ++r) {
            int idx = r * 64 + lane;
            if (idx < 304) o4[idx] = s4[idx];
        }
    } else {
        // ---- tail (unused for B=1048576, kept for generality) ----
        const int b = wrow0 + lane;
        if (b < B) {
            float a[10], c[10];
            for (int i = 0; i < 10; ++i) {
                a[i] = p1[(size_t)b * 10 + i];
                c[i] = p2[(size_t)b * 10 + i];
            }
            float s[19];
            for (int k = 0; k < 19; ++k) s[k] = 0.0f;
            for (int i = 0; i < 10; ++i)
                for (int j = 0; j < 10; ++j)
                    s[i + j] = fmaf(a[i], c[j], s[i + j]);
            float tot = 0.0f;
            for (int k = 0; k < 19; ++k) tot += s[k];
            const float den = tot + EPS;
            for (int k = 0; k < 19; ++k) out[(size_t)b * 19 + k] = s[k] / den;
        }
    }
}

extern "C" void kernel_launch(void* const* d_in, const int* in_sizes, int n_in,
                              void* d_out, int out_size, void* d_ws, size_t ws_size,
                              hipStream_t stream) {
    const float* p1 = (const float*)d_in[0];
    const float* p2 = (const float*)d_in[1];
    float* out = (float*)d_out;
    const int B = in_sizes[0] / 10;   // p1 is [B,10]

    const int grid = (B + ROWS - 1) / ROWS;   // 4096 for B=1048576
    dpl_add_kernel<<<grid, THREADS, 0, stream>>>(p1, p2, out, B);
}